// Round 1
// baseline (450.570 us; speedup 1.0000x reference)
//
#include <hip/hip_runtime.h>
#include <cstdint>
#include <cstddef>

#define D_MODEL 1024
#define HD 64
#define NH 16
#define SEQ 2048
#define NB 2

typedef __attribute__((ext_vector_type(8))) short bf8;           // 8 bf16 (4 VGPR)
typedef __attribute__((ext_vector_type(8))) unsigned short us8;
typedef __attribute__((ext_vector_type(4))) float f4;

__device__ __forceinline__ float bf2f(unsigned short u) {
  union { unsigned int i; float f; } c; c.i = ((unsigned int)u) << 16; return c.f;
}
__device__ __forceinline__ unsigned short f2bf(float x) {
  union { float f; unsigned int i; } c; c.f = x;
  unsigned int r = (c.i + 0x7FFFu + ((c.i >> 16) & 1u)) >> 16;   // RNE
  return (unsigned short)r;
}
__device__ __forceinline__ f4 mfma16(bf8 a, bf8 b, f4 c) {
  return __builtin_amdgcn_mfma_f32_16x16x32_bf16(a, b, c, 0, 0, 0);
}

// ---------------- prep: transpose + hi/lo split of the 4 weight matrices ----------------
// out: WT[n][k] hi and lo, 4 matrices concatenated.
__global__ __launch_bounds__(256) void prep_weights(
    const float* __restrict__ Wq, const float* __restrict__ Wk,
    const float* __restrict__ Wv, const float* __restrict__ Wo,
    unsigned short* __restrict__ wthi, unsigned short* __restrict__ wtlo) {
  int mat = blockIdx.z;
  const float* W = (mat == 0) ? Wq : (mat == 1) ? Wk : (mat == 2) ? Wv : Wo;
  unsigned short* oh = wthi + (size_t)mat * D_MODEL * D_MODEL;
  unsigned short* ol = wtlo + (size_t)mat * D_MODEL * D_MODEL;
  __shared__ float ls[32][33];
  int nt = blockIdx.x * 32, kt = blockIdx.y * 32;
  int i = threadIdx.x >> 5;   // 0..7
  int j = threadIdx.x & 31;
#pragma unroll
  for (int ii = 0; ii < 4; ++ii) {
    int r = i + ii * 8;
    ls[r][j] = W[(size_t)(kt + r) * D_MODEL + nt + j];
  }
  __syncthreads();
#pragma unroll
  for (int ii = 0; ii < 4; ++ii) {
    int r = i + ii * 8;                       // n-offset
    float v = ls[j][r];                       // = W[kt+j][nt+r]
    unsigned short h = f2bf(v);
    size_t o = (size_t)(nt + r) * D_MODEL + kt + j;
    oh[o] = h;
    ol[o] = f2bf(v - bf2f(h));
  }
}

// ---------------- fused q/k/v projection ----------------
// C = A @ W + b ; z=0: q (scale 1/8, hi only), z=1: k (hi+lo), z=2: v (hi only)
// grid (8, 32, 3), block 256 (4 waves, 2x2, each 64x64)
__global__ __launch_bounds__(256) void proj_kernel(
    const float* __restrict__ Qin, const float* __restrict__ Kin, const float* __restrict__ Vin,
    const unsigned short* __restrict__ wthi, const unsigned short* __restrict__ wtlo,
    const float* __restrict__ bq, const float* __restrict__ bk, const float* __restrict__ bv,
    unsigned short* __restrict__ qh, unsigned short* __restrict__ kh,
    unsigned short* __restrict__ kl, unsigned short* __restrict__ vh) {
  int z = blockIdx.z;
  const float* A = (z == 0) ? Qin : (z == 1) ? Kin : Vin;
  const unsigned short* Bh = wthi + (size_t)z * D_MODEL * D_MODEL;
  const unsigned short* Bl = wtlo + (size_t)z * D_MODEL * D_MODEL;
  const float* bias = (z == 0) ? bq : (z == 1) ? bk : bv;
  int bm = blockIdx.y, bn = blockIdx.x;
  int tid = threadIdx.x;
  int lane = tid & 63, wave = tid >> 6;
  int wr = wave >> 1, wc = wave & 1;
  int l16 = lane & 15, l4 = lane >> 4;

  __shared__ unsigned short As[128 * 40];   // A-tile hi, padded stride 40 (80B, 16B-aligned)

  f4 acc[4][4];
  const f4 zf = {0.f, 0.f, 0.f, 0.f};
#pragma unroll
  for (int m = 0; m < 4; ++m)
#pragma unroll
    for (int n = 0; n < 4; ++n) acc[m][n] = zf;

  int rr = tid >> 2, c8 = (tid & 3) * 8;

  for (int kt = 0; kt < D_MODEL; kt += 32) {
    __syncthreads();
#pragma unroll
    for (int p = 0; p < 2; ++p) {
      int row = p * 64 + rr;
      const float* src = A + (size_t)(bm * 128 + row) * D_MODEL + kt + c8;
      float4 x0 = *reinterpret_cast<const float4*>(src);
      float4 x1 = *reinterpret_cast<const float4*>(src + 4);
      us8 hv;
      hv[0] = f2bf(x0.x); hv[1] = f2bf(x0.y); hv[2] = f2bf(x0.z); hv[3] = f2bf(x0.w);
      hv[4] = f2bf(x1.x); hv[5] = f2bf(x1.y); hv[6] = f2bf(x1.z); hv[7] = f2bf(x1.w);
      *reinterpret_cast<us8*>(&As[row * 40 + c8]) = hv;
    }
    __syncthreads();
    bf8 a[4], bhf[4], blf[4];
#pragma unroll
    for (int m = 0; m < 4; ++m)
      a[m] = *reinterpret_cast<const bf8*>(&As[(wr * 64 + m * 16 + l16) * 40 + l4 * 8]);
#pragma unroll
    for (int n = 0; n < 4; ++n) {
      size_t off = (size_t)(bn * 128 + wc * 64 + n * 16 + l16) * D_MODEL + kt + l4 * 8;
      bhf[n] = *reinterpret_cast<const bf8*>(Bh + off);
      blf[n] = *reinterpret_cast<const bf8*>(Bl + off);
    }
#pragma unroll
    for (int m = 0; m < 4; ++m)
#pragma unroll
      for (int n = 0; n < 4; ++n) {
        acc[m][n] = mfma16(a[m], bhf[n], acc[m][n]);
        acc[m][n] = mfma16(a[m], blf[n], acc[m][n]);
      }
  }
#pragma unroll
  for (int n = 0; n < 4; ++n) {
    int col = bn * 128 + wc * 64 + n * 16 + l16;
    float bb = bias[col];
#pragma unroll
    for (int m = 0; m < 4; ++m) {
      int row0 = bm * 128 + wr * 64 + m * 16 + l4 * 4;
#pragma unroll
      for (int r = 0; r < 4; ++r) {
        float val = acc[m][n][r] + bb;
        size_t o = (size_t)(row0 + r) * D_MODEL + col;
        if (z == 0) {
          qh[o] = f2bf(val * 0.125f);           // fold 1/sqrt(HD)
        } else if (z == 1) {
          unsigned short hh = f2bf(val);
          kh[o] = hh; kl[o] = f2bf(val - bf2f(hh));
        } else {
          vh[o] = f2bf(val);
        }
      }
    }
  }
}

// ---------------- flash attention ----------------
// grid (S/64, NH, NB), block 256; wave w owns q-rows [qt*64+w*16, +16)
__global__ __launch_bounds__(256) void attn_kernel(
    const unsigned short* __restrict__ qh, const unsigned short* __restrict__ kh,
    const unsigned short* __restrict__ kl, const unsigned short* __restrict__ vh,
    unsigned short* __restrict__ aout) {
  int qt = blockIdx.x, h = blockIdx.y, b = blockIdx.z;
  int tid = threadIdx.x;
  int lane = tid & 63, wave = tid >> 6;
  int l16 = lane & 15, l4 = lane >> 4;

  __shared__ unsigned short vT[64 * 80];      // [d][key], XOR-swizzled keys
  __shared__ unsigned short Pl[4][16 * 80];   // per-wave P, XOR-swizzled cols

  const size_t qoff = (size_t)(b * SEQ + qt * 64 + wave * 16 + l16) * D_MODEL + h * HD + l4 * 8;
  bf8 qf0 = *reinterpret_cast<const bf8*>(qh + qoff);
  bf8 qf1 = *reinterpret_cast<const bf8*>(qh + qoff + 32);

  const f4 zf = {0.f, 0.f, 0.f, 0.f};
  f4 acc[4];
#pragma unroll
  for (int nt = 0; nt < 4; ++nt) acc[nt] = zf;
  float mrow[4] = {-1e30f, -1e30f, -1e30f, -1e30f};
  float lrow[4] = {0.f, 0.f, 0.f, 0.f};

  int sl = tid >> 2, d0 = (tid & 3) * 16;
  unsigned short* Pw = Pl[wave];

  for (int kv = 0; kv < SEQ / 64; ++kv) {
    int k0 = kv * 64;
    // V tile global loads (before barrier: no LDS touched yet)
    const unsigned short* vp = vh + (size_t)(b * SEQ + k0 + sl) * D_MODEL + h * HD + d0;
    us8 v0 = *reinterpret_cast<const us8*>(vp);
    us8 v1 = *reinterpret_cast<const us8*>(vp + 8);
    __syncthreads();   // previous iteration's vT/P reads complete
#pragma unroll
    for (int j = 0; j < 8; ++j) {
      int da = d0 + j, db = d0 + 8 + j;
      vT[da * 80 + (sl ^ (((da >> 3) & 7) << 3))] = (unsigned short)v0[j];
      vT[db * 80 + (sl ^ (((db >> 3) & 7) << 3))] = (unsigned short)v1[j];
    }
    // QK^T, 2-term split: qh·(kh + kl)
    f4 sc[4];
#pragma unroll
    for (int c = 0; c < 4; ++c) {
      size_t koff = (size_t)(b * SEQ + k0 + c * 16 + l16) * D_MODEL + h * HD + l4 * 8;
      bf8 kh0 = *reinterpret_cast<const bf8*>(kh + koff);
      bf8 kh1 = *reinterpret_cast<const bf8*>(kh + koff + 32);
      bf8 kl0 = *reinterpret_cast<const bf8*>(kl + koff);
      bf8 kl1 = *reinterpret_cast<const bf8*>(kl + koff + 32);
      f4 s = zf;
      s = mfma16(qf0, kh0, s);
      s = mfma16(qf1, kh1, s);
      s = mfma16(qf0, kl0, s);
      s = mfma16(qf1, kl1, s);
      sc[c] = s;
    }
    // online softmax (rows: l4*4+r, cols across 16 lanes)
    float alpha[4];
#pragma unroll
    for (int r = 0; r < 4; ++r) {
      float mx = fmaxf(fmaxf(sc[0][r], sc[1][r]), fmaxf(sc[2][r], sc[3][r]));
      mx = fmaxf(mx, __shfl_xor(mx, 1));
      mx = fmaxf(mx, __shfl_xor(mx, 2));
      mx = fmaxf(mx, __shfl_xor(mx, 4));
      mx = fmaxf(mx, __shfl_xor(mx, 8));
      float mn = fmaxf(mrow[r], mx);
      alpha[r] = __expf(mrow[r] - mn);
      mrow[r] = mn;
      float rs = 0.f;
#pragma unroll
      for (int c = 0; c < 4; ++c) {
        float p = __expf(sc[c][r] - mn);
        sc[c][r] = p;
        rs += p;
      }
      rs += __shfl_xor(rs, 1);
      rs += __shfl_xor(rs, 2);
      rs += __shfl_xor(rs, 4);
      rs += __shfl_xor(rs, 8);
      lrow[r] = lrow[r] * alpha[r] + rs;
    }
    // P (C-layout) -> LDS, bf16
#pragma unroll
    for (int c = 0; c < 4; ++c)
#pragma unroll
      for (int r = 0; r < 4; ++r) {
        int prow = l4 * 4 + r;
        Pw[prow * 80 + ((c * 16 + l16) ^ ((prow & 7) << 3))] = f2bf(sc[c][r]);
      }
    __syncthreads();   // vT + P visible
    // rescale running accumulator
#pragma unroll
    for (int nt = 0; nt < 4; ++nt) {
      acc[nt][0] *= alpha[0]; acc[nt][1] *= alpha[1];
      acc[nt][2] *= alpha[2]; acc[nt][3] *= alpha[3];
    }
    // PV: A = P (A-layout read), B = vT
    bf8 pa0 = *reinterpret_cast<const bf8*>(&Pw[l16 * 80 + ((l4 * 8) ^ ((l16 & 7) << 3))]);
    bf8 pa1 = *reinterpret_cast<const bf8*>(&Pw[l16 * 80 + ((32 + l4 * 8) ^ ((l16 & 7) << 3))]);
#pragma unroll
    for (int nt = 0; nt < 4; ++nt) {
      int d = nt * 16 + l16;
      int f = (d >> 3) & 7;
      bf8 vb0 = *reinterpret_cast<const bf8*>(&vT[d * 80 + ((l4 * 8) ^ (f << 3))]);
      bf8 vb1 = *reinterpret_cast<const bf8*>(&vT[d * 80 + ((32 + l4 * 8) ^ (f << 3))]);
      acc[nt] = mfma16(pa0, vb0, acc[nt]);
      acc[nt] = mfma16(pa1, vb1, acc[nt]);
    }
  }
  // epilogue: normalize, write attn_out hi-bf16 [B,S,D]
#pragma unroll
  for (int nt = 0; nt < 4; ++nt) {
    int col = h * HD + nt * 16 + l16;
#pragma unroll
    for (int r = 0; r < 4; ++r) {
      int row = b * SEQ + qt * 64 + wave * 16 + l4 * 4 + r;
      aout[(size_t)row * D_MODEL + col] = f2bf(acc[nt][r] / lrow[r]);
    }
  }
}

// ---------------- output projection: out = attn @ Wo + bo (fp32 out) ----------------
// grid (8, 32), block 256; LDS-free (A already bf16)
__global__ __launch_bounds__(256) void out_gemm(
    const unsigned short* __restrict__ ah, const unsigned short* __restrict__ wthi,
    const unsigned short* __restrict__ wtlo, const float* __restrict__ bo,
    float* __restrict__ out) {
  const unsigned short* Bh = wthi + (size_t)3 * D_MODEL * D_MODEL;
  const unsigned short* Bl = wtlo + (size_t)3 * D_MODEL * D_MODEL;
  int bm = blockIdx.y, bn = blockIdx.x;
  int tid = threadIdx.x, lane = tid & 63, wave = tid >> 6;
  int wr = wave >> 1, wc = wave & 1;
  int l16 = lane & 15, l4 = lane >> 4;
  f4 acc[4][4];
  const f4 zf = {0.f, 0.f, 0.f, 0.f};
#pragma unroll
  for (int m = 0; m < 4; ++m)
#pragma unroll
    for (int n = 0; n < 4; ++n) acc[m][n] = zf;

  for (int kt = 0; kt < D_MODEL; kt += 32) {
    bf8 a[4], bhf[4], blf[4];
#pragma unroll
    for (int m = 0; m < 4; ++m)
      a[m] = *reinterpret_cast<const bf8*>(
          ah + (size_t)(bm * 128 + wr * 64 + m * 16 + l16) * D_MODEL + kt + l4 * 8);
#pragma unroll
    for (int n = 0; n < 4; ++n) {
      size_t off = (size_t)(bn * 128 + wc * 64 + n * 16 + l16) * D_MODEL + kt + l4 * 8;
      bhf[n] = *reinterpret_cast<const bf8*>(Bh + off);
      blf[n] = *reinterpret_cast<const bf8*>(Bl + off);
    }
#pragma unroll
    for (int m = 0; m < 4; ++m)
#pragma unroll
      for (int n = 0; n < 4; ++n) {
        acc[m][n] = mfma16(a[m], bhf[n], acc[m][n]);
        acc[m][n] = mfma16(a[m], blf[n], acc[m][n]);
      }
  }
#pragma unroll
  for (int n = 0; n < 4; ++n) {
    int col = bn * 128 + wc * 64 + n * 16 + l16;
    float bb = bo[col];
#pragma unroll
    for (int m = 0; m < 4; ++m) {
      int row0 = bm * 128 + wr * 64 + m * 16 + l4 * 4;
#pragma unroll
      for (int r = 0; r < 4; ++r)
        out[(size_t)(row0 + r) * D_MODEL + col] = acc[m][n][r] + bb;
    }
  }
}

extern "C" void kernel_launch(void* const* d_in, const int* in_sizes, int n_in,
                              void* d_out, int out_size, void* d_ws, size_t ws_size,
                              hipStream_t stream) {
  const float* Q  = (const float*)d_in[0];
  const float* K  = (const float*)d_in[1];
  const float* V  = (const float*)d_in[2];
  const float* Wq = (const float*)d_in[3];
  const float* bq = (const float*)d_in[4];
  const float* Wk = (const float*)d_in[5];
  const float* bk = (const float*)d_in[6];
  const float* Wv = (const float*)d_in[7];
  const float* bv = (const float*)d_in[8];
  const float* Wo = (const float*)d_in[9];
  const float* bo = (const float*)d_in[10];
  float* out = (float*)d_out;

  // workspace layout (56 MB total, fully rewritten every call)
  unsigned char* ws = (unsigned char*)d_ws;
  const size_t MB = 1024 * 1024;
  unsigned short* wthi = (unsigned short*)(ws);             // 4x [n][k] hi   (8 MB)
  unsigned short* wtlo = (unsigned short*)(ws + 8 * MB);    // 4x [n][k] lo   (8 MB)
  unsigned short* qh   = (unsigned short*)(ws + 16 * MB);   // q hi  [B,S,D]  (8 MB)
  unsigned short* kh   = (unsigned short*)(ws + 24 * MB);   // k hi           (8 MB)
  unsigned short* kl   = (unsigned short*)(ws + 32 * MB);   // k lo           (8 MB)
  unsigned short* vh   = (unsigned short*)(ws + 40 * MB);   // v hi           (8 MB)
  unsigned short* ah   = (unsigned short*)(ws + 48 * MB);   // attn out hi    (8 MB)

  prep_weights<<<dim3(32, 32, 4), 256, 0, stream>>>(Wq, Wk, Wv, Wo, wthi, wtlo);
  proj_kernel<<<dim3(8, 32, 3), 256, 0, stream>>>(Q, K, V, wthi, wtlo, bq, bk, bv,
                                                  qh, kh, kl, vh);
  attn_kernel<<<dim3(32, NH, NB), 256, 0, stream>>>(qh, kh, kl, vh, ah);
  out_gemm<<<dim3(8, 32), 256, 0, stream>>>(ah, wthi, wtlo, bo, out);
}